// Round 16
// baseline (513.462 us; speedup 1.0000x reference)
//
#include <hip/hip_runtime.h>
#include <hip/hip_bf16.h>

#define Bc 16
#define Hc 56
#define Wcc 56
#define Cc 192
#define NHc 6
#define Lc 3136
#define DHc 32
#define HIDc 768
#define NHEAD 96          // B*NH
#define Sc 32             // chunk length
#define NCHUNK 98         // chunks per head (98*32 = 3136)
#define NPAIR (NHEAD*NCHUNK)
#define ROWS (Bc*Lc)      // 50176
#define GR2 (ROWS/2)      // 25088 rows per MLP group (8 images)
#define ETAc (1.0f/32.0f)

typedef unsigned short u16;
typedef unsigned int u32;
typedef __attribute__((ext_vector_type(8))) short bf16x8;
typedef __attribute__((ext_vector_type(4))) float f32x4;
typedef __attribute__((ext_vector_type(16))) float f32x16;

__device__ __forceinline__ float b2f(u16 v){ u32 u = ((u32)v)<<16; float f; __builtin_memcpy(&f,&u,4); return f; }
__device__ __forceinline__ u16 f2b(float f){ u32 u; __builtin_memcpy(&u,&f,4); u32 r = u + 0x7FFFu + ((u>>16)&1u); return (u16)(r>>16); }
__device__ __forceinline__ f32x16 zero16(){ f32x16 z = {0,0,0,0,0,0,0,0,0,0,0,0,0,0,0,0}; return z; }

__device__ __forceinline__ void make_bfrags(const f32x16& t, int hi, bf16x8& b1, bf16x8& b2){
  u32 P[8], S[8];
  #pragma unroll
  for (int q=0;q<4;q++){
    #pragma unroll
    for (int j=0;j<2;j++){
      u32 r; float lo = t[4*q+2*j], hv = t[4*q+2*j+1];
      asm("v_cvt_pk_bf16_f32 %0, %1, %2" : "=v"(r) : "v"(lo), "v"(hv));
      P[2*q+j] = r;
    }
  }
  #pragma unroll
  for (int i=0;i<8;i++) S[i] = (u32)__shfl_xor((int)P[i], 32);
  union { u32 u[4]; bf16x8 v; } f1, f2;
  if (hi==0){ f1.u[0]=P[0]; f1.u[1]=P[1]; f1.u[2]=S[0]; f1.u[3]=S[1];
              f2.u[0]=P[4]; f2.u[1]=P[5]; f2.u[2]=S[4]; f2.u[3]=S[5]; }
  else      { f1.u[0]=S[2]; f1.u[1]=S[3]; f1.u[2]=P[2]; f1.u[3]=P[3];
              f2.u[0]=S[6]; f2.u[1]=S[7]; f2.u[2]=P[6]; f2.u[3]=P[7]; }
  b1 = f1.v; b2 = f2.v;
}

// ---------------- fused weight prep ----------------
__global__ __launch_bounds__(256) void prep_kernel(
    const float* __restrict__ qkvw, const float* __restrict__ projw,
    const float* __restrict__ fc1w, const float* __restrict__ fc2w,
    const float* __restrict__ dwcw, const float* __restrict__ cpew,
    u16* __restrict__ wbqkv, u16* __restrict__ wbproj, u16* __restrict__ wbfc1,
    u16* __restrict__ wbfc2, float* __restrict__ dwt9, float* __restrict__ cwt9){
  int i = blockIdx.x*256 + threadIdx.x;
  if (i < 110592) wbqkv[i] = f2b(qkvw[i]);
  else if (i < 147456){ int j=i-110592; wbproj[j] = f2b(projw[j]); }
  else if (i < 294912){ int j=i-147456; wbfc1[j] = f2b(fc1w[j]); }
  else if (i < 442368){ int j=i-294912; wbfc2[j] = f2b(fc2w[j]); }
  else if (i < 449280){ int j=i-442368; int ch=j/9, t=j-ch*9; dwt9[t*HIDc+ch] = dwcw[j]; }
  else if (i < 451008){ int j=i-449280; int ch=j/9, t=j-ch*9; cwt9[t*Cc+ch] = cpew[j]; }
}

// ---------------- rope tables ----------------
__global__ __launch_bounds__(256) void rope_tab_kernel(float* __restrict__ ct, float* __restrict__ st){
  int i = blockIdx.x*256 + threadIdx.x;   // < Lc*96
  int l = i/96, p = i - l*96;
  int h = l/Wcc, w = l - h*Wcc;
  int kk = (p<48)? p : p-48;
  float th = powf(10000.f, -(float)kk/48.f);
  float ang = (float)((p<48)? h : w) * th;
  ct[i] = cosf(ang);
  st[i] = sinf(ang);
}

// ---------------- CPE depthwise conv + LN1 fused ----------------
__global__ __launch_bounds__(192) void cpe_ln_kernel(const float* __restrict__ x, const float* __restrict__ cwt9,
                                                     const float* __restrict__ bs, const float* __restrict__ g,
                                                     const float* __restrict__ b,
                                                     u16* __restrict__ x1, u16* __restrict__ xn){
  __shared__ float ps[192], pq[192], smu[8], srs[8];
  int tid = threadIdx.x;
  int rl = tid/24, sub = tid - rl*24, ch0 = sub*8;
  int row = blockIdx.x*8 + rl;
  int l = row % Lc; int h = l/Wcc, w = l - h*Wcc;
  const float* xp = x + (size_t)row*Cc + ch0;
  float acc[8];
  { f32x4 b0 = *(const f32x4*)(bs+ch0), b1v = *(const f32x4*)(bs+ch0+4);
    acc[0]=b0[0];acc[1]=b0[1];acc[2]=b0[2];acc[3]=b0[3];
    acc[4]=b1v[0];acc[5]=b1v[1];acc[6]=b1v[2];acc[7]=b1v[3]; }
  #pragma unroll
  for (int kh=0;kh<3;kh++){
    int hh = h+kh-1; if (hh<0 || hh>=Hc) continue;
    #pragma unroll
    for (int kw=0;kw<3;kw++){
      int ww = w+kw-1; if (ww<0 || ww>=Wcc) continue;
      const float* ip = xp + ((kh-1)*Wcc + (kw-1))*Cc;
      f32x4 i0 = *(const f32x4*)ip, i1 = *(const f32x4*)(ip+4);
      const float* wp = cwt9 + (kh*3+kw)*Cc + ch0;
      f32x4 w0 = *(const f32x4*)wp, w1 = *(const f32x4*)(wp+4);
      acc[0] += i0[0]*w0[0]; acc[1] += i0[1]*w0[1]; acc[2] += i0[2]*w0[2]; acc[3] += i0[3]*w0[3];
      acc[4] += i1[0]*w1[0]; acc[5] += i1[1]*w1[1]; acc[6] += i1[2]*w1[2]; acc[7] += i1[3]*w1[3];
    }
  }
  float val[8];
  { f32x4 c0 = *(const f32x4*)xp, c1 = *(const f32x4*)(xp+4);
    val[0]=c0[0]+acc[0]; val[1]=c0[1]+acc[1]; val[2]=c0[2]+acc[2]; val[3]=c0[3]+acc[3];
    val[4]=c1[0]+acc[4]; val[5]=c1[1]+acc[5]; val[6]=c1[2]+acc[6]; val[7]=c1[3]+acc[7]; }
  float s8=0.f, q8=0.f;
  #pragma unroll
  for (int j=0;j<8;j++){ s8 += val[j]; q8 += val[j]*val[j]; }
  ps[tid]=s8; pq[tid]=q8;
  __syncthreads();
  if (tid < 8){
    float s=0.f, q=0.f;
    #pragma unroll
    for (int k=0;k<24;k++){ s += ps[tid*24+k]; q += pq[tid*24+k]; }
    float mu = s*(1.f/Cc);
    float var = q*(1.f/Cc) - mu*mu;
    smu[tid] = mu; srs[tid] = rsqrtf(var + 1e-5f);
  }
  __syncthreads();
  float mu = smu[rl], rstd = srs[rl];
  union { bf16x8 v; u16 s[8]; } o1, o2;
  f32x4 g0 = *(const f32x4*)(g+ch0), g1 = *(const f32x4*)(g+ch0+4);
  f32x4 bb0 = *(const f32x4*)(b+ch0), bb1 = *(const f32x4*)(b+ch0+4);
  float gg[8] = {g0[0],g0[1],g0[2],g0[3],g1[0],g1[1],g1[2],g1[3]};
  float bbv[8] = {bb0[0],bb0[1],bb0[2],bb0[3],bb1[0],bb1[1],bb1[2],bb1[3]};
  #pragma unroll
  for (int j=0;j<8;j++){
    o1.s[j] = f2b(val[j]);
    o2.s[j] = f2b((val[j]-mu)*rstd*gg[j] + bbv[j]);
  }
  *(bf16x8*)(x1 + (size_t)row*Cc + ch0) = o1.v;
  *(bf16x8*)(xn + (size_t)row*Cc + ch0) = o2.v;
}

// ---------------- LDS-staged GEMM, BLKM=64 ----------------
// MODE 0 (NB=3,KT=192): qkv + fused rope (nb0:q, nb1:k, nb2:v)
// MODE 1 (NB=1,KT=192): proj: x2b = v + b2f(residb) AND fused LN2 -> xnout
// MODE 2 (NB=4,KT=192): fc1: bf16 out = gelu(v), width HIDc
// MODE 3 (NB=1,KT=768): fc2: fp32 out = v + b2f(residb)
template<int MODE, int NB, int KT>
__global__ __launch_bounds__(256) void gemm_kernel(
    const u16* __restrict__ A, const u16* __restrict__ Wt,
    const float* __restrict__ bias,
    float* __restrict__ outf, u16* __restrict__ outb, u16* __restrict__ vdst,
    const u16* __restrict__ residb,
    const float* __restrict__ ct, const float* __restrict__ st,
    u16* __restrict__ q_s, u16* __restrict__ k_s,
    const float* __restrict__ lng, const float* __restrict__ lnb, u16* __restrict__ xnout)
{
  constexpr int NCH = KT/192;
  __shared__ __align__(16) u16 As[64*200];
  __shared__ __align__(16) u16 Osu[64*200];
  float* Os32 = (float*)Osu;
  int tid = threadIdx.x;
  int wid = tid>>6, lane = tid&63;
  int wr = wid>>1, wc = wid&1;
  int m0 = blockIdx.x*64;
  int ar = lane&15, kg = lane>>4;

  if constexpr (NCH == 1){
    #pragma unroll
    for (int j=0;j<6;j++){
      int g = j*256 + tid;
      int grow = g/24, gcol = (g - grow*24)*8;
      *(bf16x8*)(As + grow*200 + gcol) = *(const bf16x8*)(A + (size_t)(m0+grow)*192 + gcol);
    }
    __syncthreads();
    #pragma unroll
    for (int nb=0; nb<NB; nb++){
      const int nblk = nb*192;
      const int n0 = nblk + wc*96;
      f32x4 acc[2][6];
      #pragma unroll
      for (int f=0;f<2;f++)
        #pragma unroll
        for (int c=0;c<6;c++){ f32x4 z={0.f,0.f,0.f,0.f}; acc[f][c]=z; }
      bf16x8 bcur[6], bnxt[6];
      #pragma unroll
      for (int c=0;c<6;c++) bcur[c] = *(const bf16x8*)(Wt + (size_t)(n0 + c*16 + ar)*192 + kg*8);
      #pragma unroll
      for (int kc=0;kc<6;kc++){
        if (kc < 5){
          #pragma unroll
          for (int c=0;c<6;c++) bnxt[c] = *(const bf16x8*)(Wt + (size_t)(n0 + c*16 + ar)*192 + (kc+1)*32 + kg*8);
        }
        bf16x8 af[2];
        #pragma unroll
        for (int f=0;f<2;f++)
          af[f] = *(const bf16x8*)(As + (wr*32 + f*16 + ar)*200 + kc*32 + kg*8);
        #pragma unroll
        for (int f=0;f<2;f++)
          #pragma unroll
          for (int c=0;c<6;c++)
            acc[f][c] = __builtin_amdgcn_mfma_f32_16x16x32_bf16(af[f], bcur[c], acc[f][c], 0,0,0);
        #pragma unroll
        for (int c=0;c<6;c++) bcur[c] = bnxt[c];
      }
      __syncthreads();   // protects Osu reuse
      #pragma unroll
      for (int f=0;f<2;f++){
        #pragma unroll
        for (int c=0;c<6;c++){
          float bv = bias[n0 + c*16 + ar];
          #pragma unroll
          for (int j=0;j<4;j++){
            float v = acc[f][c][j] + bv;
            if (MODE==2) v = 0.5f*v*(1.f + erff(v*0.70710678118654752f));
            Osu[(wr*32 + f*16 + kg*4 + j)*200 + wc*96 + c*16 + ar] = f2b(v);
          }
        }
      }
      __syncthreads();
      #pragma unroll
      for (int j=0;j<6;j++){
        int g = j*256 + tid;
        int grow = g/24, gcol = (g - grow*24)*8;
        bf16x8 v = *(const bf16x8*)(Osu + grow*200 + gcol);
        int row = m0 + grow;
        if (MODE==2){
          *(bf16x8*)(outb + (size_t)row*HIDc + nblk + gcol) = v;
        } else if (MODE==1){
          bf16x8 rv = *(const bf16x8*)(residb + (size_t)row*Cc + gcol);
          union { bf16x8 v; u16 s[8]; } o;
          #pragma unroll
          for (int t=0;t<8;t++) o.s[t] = f2b(b2f((u16)v[t]) + b2f((u16)rv[t]));
          *(bf16x8*)(outb + (size_t)row*Cc + gcol) = o.v;
          *(bf16x8*)(Osu + grow*200 + gcol) = o.v;   // stash x2 (bf16) for fused LN2
        } else {
          int bb = row/Lc; int l = row - bb*Lc;
          int nh = gcol>>5, d = gcol&31;
          if (nb < 2){
            const bool isq = (nb == 0);
            int p0 = gcol>>1;
            f32x4 cv = *(const f32x4*)(ct + l*96 + p0);
            f32x4 sv = *(const f32x4*)(st + l*96 + p0);
            float sc = isq ? 0.1767766952966369f : 1.0f;
            union { bf16x8 v; u16 s[8]; } o;
            #pragma unroll
            for (int t=0;t<4;t++){
              float re = b2f((u16)v[2*t]), im = b2f((u16)v[2*t+1]);
              o.s[2*t]   = f2b((cv[t]*re - sv[t]*im)*sc);
              o.s[2*t+1] = f2b((sv[t]*re + cv[t]*im)*sc);
            }
            u16* dst = (isq ? q_s : k_s) + (((size_t)(bb*NHc+nh))*Lc + l)*DHc + d;
            *(bf16x8*)dst = o.v;
          } else {
            *(bf16x8*)(vdst + (((size_t)(bb*NHc+nh))*Lc + l)*DHc + d) = v;
          }
        }
      }
    }
    // ---- fused LN2 (MODE 1): per-row stats over Osu (x2 bf16), write xnout ----
    if (MODE==1){
      __syncthreads();
      int rowl = tid>>2, q = tid&3;        // 4 threads per row, 48 cols each
      const u16* orow = Osu + rowl*200 + q*48;
      float s=0.f, qq=0.f;
      #pragma unroll
      for (int c=0;c<48;c++){ float v = b2f(orow[c]); s += v; qq += v*v; }
      s += __shfl_xor(s,1); qq += __shfl_xor(qq,1);
      s += __shfl_xor(s,2); qq += __shfl_xor(qq,2);
      float mu = s*(1.f/192.f);
      float rstd = rsqrtf(qq*(1.f/192.f) - mu*mu + 1e-5f);
      int row = m0 + rowl;
      #pragma unroll
      for (int c8=0;c8<6;c8++){
        union { bf16x8 v; u16 s[8]; } ox;
        #pragma unroll
        for (int t=0;t<8;t++){
          int col = q*48 + c8*8 + t;
          ox.s[t] = f2b((b2f(orow[c8*8+t])-mu)*rstd*lng[col] + lnb[col]);
        }
        *(bf16x8*)(xnout + (size_t)row*Cc + q*48 + c8*8) = ox.v;
      }
    }
  } else {
    // ---- NCH>1 (fc2): chunk-accumulate ----
    const int n0 = wc*96;
    f32x4 acc[2][6];
    #pragma unroll
    for (int f=0;f<2;f++)
      #pragma unroll
      for (int c=0;c<6;c++){ f32x4 z={0.f,0.f,0.f,0.f}; acc[f][c]=z; }
    bf16x8 bcur[6], bnxt[6];
    #pragma unroll
    for (int c=0;c<6;c++) bcur[c] = *(const bf16x8*)(Wt + (size_t)(n0 + c*16 + ar)*KT + kg*8);
    #pragma unroll
    for (int ch=0; ch<NCH; ch++){
      if (ch>0) __syncthreads();
      #pragma unroll
      for (int j=0;j<6;j++){
        int g = j*256 + tid;
        int grow = g/24, gcol = (g - grow*24)*8;
        *(bf16x8*)(As + grow*200 + gcol) = *(const bf16x8*)(A + (size_t)(m0+grow)*KT + ch*192 + gcol);
      }
      __syncthreads();
      #pragma unroll
      for (int kc=0;kc<6;kc++){
        int s = ch*6 + kc;
        if (s+1 < NCH*6){
          int koff = ((s+1)/6)*192 + ((s+1)%6)*32 + kg*8;
          #pragma unroll
          for (int c=0;c<6;c++) bnxt[c] = *(const bf16x8*)(Wt + (size_t)(n0 + c*16 + ar)*KT + koff);
        }
        bf16x8 af[2];
        #pragma unroll
        for (int f=0;f<2;f++)
          af[f] = *(const bf16x8*)(As + (wr*32 + f*16 + ar)*200 + kc*32 + kg*8);
        #pragma unroll
        for (int f=0;f<2;f++)
          #pragma unroll
          for (int c=0;c<6;c++)
            acc[f][c] = __builtin_amdgcn_mfma_f32_16x16x32_bf16(af[f], bcur[c], acc[f][c], 0,0,0);
        #pragma unroll
        for (int c=0;c<6;c++) bcur[c] = bnxt[c];
      }
    }
    #pragma unroll
    for (int half=0; half<2; half++){
      __syncthreads();
      if (wc==half){
        #pragma unroll
        for (int f=0;f<2;f++){
          #pragma unroll
          for (int c=0;c<6;c++){
            float bv = bias[n0 + c*16 + ar];
            #pragma unroll
            for (int j=0;j<4;j++)
              Os32[(wr*32 + f*16 + kg*4 + j)*100 + c*16 + ar] = acc[f][c][j] + bv;
          }
        }
      }
      __syncthreads();
      #pragma unroll
      for (int j=0;j<6;j++){
        int g = j*256 + tid;
        int grow = g/24, qcol = (g - grow*24)*4;
        f32x4 v = *(const f32x4*)(Os32 + grow*100 + qcol);
        int row = m0 + grow, colg = half*96 + qcol;
        const u16* rp = residb + (size_t)row*Cc + colg;
        v[0] += b2f(rp[0]); v[1] += b2f(rp[1]); v[2] += b2f(rp[2]); v[3] += b2f(rp[3]);
        *(f32x4*)(outf + (size_t)row*Cc + colg) = v;
      }
    }
  }
}

// ---------------- MLP depthwise conv (HID=768) + gelu ----------------
__global__ __launch_bounds__(256) void dwc_kernel(const u16* __restrict__ h1, const float* __restrict__ wt9,
                                                  const float* __restrict__ bs, u16* __restrict__ h2, int row0){
  int gid = blockIdx.x*256 + threadIdx.x;   // < GR2*96
  int cg = gid % 96; int lrow = gid / 96; int ch0 = cg*8;
  int row = row0 + lrow;
  int l = row % Lc; int h = l/Wcc, w = l - h*Wcc;
  const u16* hp = h1 + (size_t)lrow*HIDc + ch0;
  float acc[8];
  { f32x4 b0 = *(const f32x4*)(bs+ch0), b1v = *(const f32x4*)(bs+ch0+4);
    acc[0]=b0[0];acc[1]=b0[1];acc[2]=b0[2];acc[3]=b0[3];
    acc[4]=b1v[0];acc[5]=b1v[1];acc[6]=b1v[2];acc[7]=b1v[3]; }
  #pragma unroll
  for (int kh=0;kh<3;kh++){
    int hh = h+kh-1; if (hh<0 || hh>=Hc) continue;
    #pragma unroll
    for (int kw=0;kw<3;kw++){
      int ww = w+kw-1; if (ww<0 || ww>=Wcc) continue;
      bf16x8 iv = *(const bf16x8*)(hp + ((kh-1)*Wcc + (kw-1))*HIDc);
      const float* wp = wt9 + (kh*3+kw)*HIDc + ch0;
      f32x4 w0 = *(const f32x4*)wp, w1 = *(const f32x4*)(wp+4);
      acc[0] += b2f((u16)iv[0])*w0[0]; acc[1] += b2f((u16)iv[1])*w0[1];
      acc[2] += b2f((u16)iv[2])*w0[2]; acc[3] += b2f((u16)iv[3])*w0[3];
      acc[4] += b2f((u16)iv[4])*w1[0]; acc[5] += b2f((u16)iv[5])*w1[1];
      acc[6] += b2f((u16)iv[6])*w1[2]; acc[7] += b2f((u16)iv[7])*w1[3];
    }
  }
  bf16x8 cv = *(const bf16x8*)hp;
  union { bf16x8 v; u16 s[8]; } ov;
  #pragma unroll
  for (int j=0;j<8;j++){
    float v = b2f((u16)cv[j]) + acc[j];
    ov.s[j] = f2b(0.5f*v*(1.f + erff(v*0.70710678118654752f)));
  }
  *(bf16x8*)(h2 + (size_t)lrow*HIDc + ch0) = ov.v;
}

// ---------------- phase A: per (head,chunk) solve -> U, -R, A'=-K^T R (frags), B=K^T U ----------------
__global__ __launch_bounds__(64) void ttta_kernel(const u16* __restrict__ k_s, const u16* __restrict__ v_s,
                                                  u16* __restrict__ u_s, u16* __restrict__ rn_s,
                                                  u16* __restrict__ af_s, u16* __restrict__ bc_s){
  __shared__ float Gl[1024];
  __shared__ u16 LK[32*40];
  __shared__ float LU[32*33];
  __shared__ float LR[32*33];
  int pair = blockIdx.x;
  int head = pair / NCHUNK;
  int l0 = (pair - head*NCHUNK) * Sc;
  int lane = threadIdx.x; int rr = lane&31; int hi = lane>>5; int ks = hi*8;
  const u16* kb = k_s + ((size_t)head*Lc + l0)*DHc;
  bf16x8 a0 = *(const bf16x8*)(kb + rr*32 + ks);
  bf16x8 a1 = *(const bf16x8*)(kb + rr*32 + 16 + ks);
  *(bf16x8*)(LK + rr*40 + ks) = a0;
  *(bf16x8*)(LK + rr*40 + 16 + ks) = a1;
  f32x16 g = zero16();
  g = __builtin_amdgcn_mfma_f32_32x32x16_bf16(a0, a0, g, 0,0,0);
  g = __builtin_amdgcn_mfma_f32_32x32x16_bf16(a1, a1, g, 0,0,0);
  #pragma unroll
  for (int reg=0;reg<16;reg++){
    int i = (reg&3) + 8*(reg>>2) + 4*hi;
    Gl[i*32 + rr] = ETAc * g[reg];
  }
  __syncthreads();
  float X[32];
  if (lane < 32){
    #pragma unroll
    for (int i=0;i<32;i++) X[i] = ETAc * b2f(v_s[((size_t)head*Lc + l0 + i)*DHc + lane]);
  } else {
    int m = lane-32;
    #pragma unroll
    for (int i=0;i<32;i++) X[i] = ETAc * b2f(kb[i*32 + m]);
  }
  #pragma unroll
  for (int i=1;i<32;i++){
    float a = X[i];
    #pragma unroll
    for (int j=0;j<i;j++) a -= Gl[i*32+j]*X[j];
    X[i] = a;
  }
  if (lane < 32){
    u16* dst = u_s + (size_t)pair*1024 + lane;
    #pragma unroll
    for (int i=0;i<32;i++) dst[i*32] = f2b(X[i]);
    #pragma unroll
    for (int i=0;i<32;i++) LU[lane*33 + i] = X[i];
  } else {
    u16* dst = rn_s + (size_t)pair*1024 + (lane&31);
    #pragma unroll
    for (int i=0;i<32;i++) dst[i*32] = f2b(-X[i]);
    #pragma unroll
    for (int i=0;i<32;i++) LR[(lane&31)*33 + i] = X[i];
  }
  __syncthreads();
  union { bf16x8 v; u16 s[8]; } kc1, kc2, uc1, uc2, rc1, rc2;
  #pragma unroll
  for (int s=0;s<8;s++){
    kc1.s[s] = LK[(ks+s)*40 + rr];
    kc2.s[s] = LK[(16+ks+s)*40 + rr];
    uc1.s[s] = f2b(LU[rr*33 + ks+s]);
    uc2.s[s] = f2b(LU[rr*33 + 16+ks+s]);
    rc1.s[s] = f2b(LR[rr*33 + ks+s]);
    rc2.s[s] = f2b(LR[rr*33 + 16+ks+s]);
  }
  f32x16 bacc = zero16();
  bacc = __builtin_amdgcn_mfma_f32_32x32x16_bf16(kc1.v, uc1.v, bacc, 0,0,0);
  bacc = __builtin_amdgcn_mfma_f32_32x32x16_bf16(kc2.v, uc2.v, bacc, 0,0,0);
  union { bf16x8 v; u16 s[8]; } bo1, bo2;
  #pragma unroll
  for (int r=0;r<8;r++){ bo1.s[r] = f2b(bacc[r]); bo2.s[r] = f2b(bacc[8+r]); }
  *(bf16x8*)(bc_s + (size_t)pair*1024 + lane*16) = bo1.v;
  *(bf16x8*)(bc_s + (size_t)pair*1024 + lane*16 + 8) = bo2.v;
  f32x16 aacc = zero16();
  aacc = __builtin_amdgcn_mfma_f32_32x32x16_bf16(rc1.v, kc1.v, aacc, 0,0,0);
  aacc = __builtin_amdgcn_mfma_f32_32x32x16_bf16(rc2.v, kc2.v, aacc, 0,0,0);
  f32x16 an;
  #pragma unroll
  for (int r=0;r<16;r++) an[r] = -aacc[r];
  bf16x8 f1, f2;
  make_bfrags(an, hi, f1, f2);
  *(bf16x8*)(af_s + (size_t)pair*1024 + lane*16) = f1;
  *(bf16x8*)(af_s + (size_t)pair*1024 + lane*16 + 8) = f2;
}

// ---------------- phase B: MFMA affine scan  T_{c+1} = T_c + A'_c T_c + B_c ----------------
__global__ __launch_bounds__(64) void tttb_kernel(const u16* __restrict__ af_s, const u16* __restrict__ bc_s,
                                                  const float* __restrict__ W0, u16* __restrict__ w_snap){
  int head = blockIdx.x; int nh = head % NHc;
  int lane = threadIdx.x; int rr = lane&31; int hi = lane>>5;
  f32x16 T;
  const float* w0r = W0 + nh*1024 + rr*32 + 4*hi;
  #pragma unroll
  for (int q=0;q<4;q++){
    f32x4 v = *(const f32x4*)(w0r + 8*q);
    T[4*q+0]=v[0]; T[4*q+1]=v[1]; T[4*q+2]=v[2]; T[4*q+3]=v[3];
  }
  size_t hb = (size_t)head*NCHUNK;
  const bf16x8* afp = (const bf16x8*)(af_s + hb*1024);
  const bf16x8* bcp = (const bf16x8*)(bc_s + hb*1024);
  bf16x8 A1 = afp[lane*2], A2 = afp[lane*2+1];
  bf16x8 Bv1 = bcp[lane*2], Bv2 = bcp[lane*2+1];
  bf16x8 b1, b2;
  make_bfrags(T, hi, b1, b2);
  for (int c=0;c<NCHUNK;c++){
    bf16x8 nA1=A1, nA2=A2, nB1=Bv1, nB2=Bv2;
    if (c+1 < NCHUNK){
      int base = (c+1)*128 + lane*2;
      nA1 = afp[base]; nA2 = afp[base+1];
      nB1 = bcp[base]; nB2 = bcp[base+1];
    }
    u16* wrow = w_snap + (hb + c)*1024 + rr*32;
    *(bf16x8*)(wrow + hi*8) = b1;
    *(bf16x8*)(wrow + 16 + hi*8) = b2;
    f32x16 acc;
    #pragma unroll
    for (int r=0;r<8;r++){ acc[r] = T[r] + b2f((u16)Bv1[r]); acc[8+r] = T[8+r] + b2f((u16)Bv2[r]); }
    acc = __builtin_amdgcn_mfma_f32_32x32x16_bf16(A1, b1, acc, 0,0,0);
    acc = __builtin_amdgcn_mfma_f32_32x32x16_bf16(A2, b2, acc, 0,0,0);
    T = acc;
    make_bfrags(T, hi, b1, b2);
    A1=nA1; A2=nA2; Bv1=nB1; Bv2=nB2;
  }
}

// ---------------- phase C: O = Q*T0 + tril(Q K^T)*(U - R*T0) ----------------
__global__ __launch_bounds__(64) void tttc_kernel(const u16* __restrict__ q_s, const u16* __restrict__ k_s,
                                                  const u16* __restrict__ w_snap, const u16* __restrict__ u_s,
                                                  const u16* __restrict__ rn_s, u16* __restrict__ o_bf){
  __shared__ __align__(16) u16 Pl[32*40];
  int pair = blockIdx.x;
  int head = pair / NCHUNK;
  int ch = pair - head*NCHUNK;
  int l0 = ch*Sc;
  int lane = threadIdx.x; int rr = lane&31; int hi = lane>>5; int ks = hi*8;
  const u16* qb = q_s + ((size_t)head*Lc + l0)*DHc;
  const u16* kb = k_s + ((size_t)head*Lc + l0)*DHc;
  bf16x8 q0 = *(const bf16x8*)(qb + rr*32 + ks);
  bf16x8 q1 = *(const bf16x8*)(qb + rr*32 + 16 + ks);
  bf16x8 k0 = *(const bf16x8*)(kb + rr*32 + ks);
  bf16x8 k1 = *(const bf16x8*)(kb + rr*32 + 16 + ks);
  f32x16 p = zero16();
  p = __builtin_amdgcn_mfma_f32_32x32x16_bf16(q0, k0, p, 0,0,0);
  p = __builtin_amdgcn_mfma_f32_32x32x16_bf16(q1, k1, p, 0,0,0);
  #pragma unroll
  for (int reg=0;reg<16;reg++){
    int i = (reg&3)+8*(reg>>2)+4*hi;
    Pl[i*40+rr] = (rr<=i) ? f2b(p[reg]) : (u16)0;
  }
  const u16* wsb = w_snap + (size_t)pair*1024;
  bf16x8 tb0 = *(const bf16x8*)(wsb + rr*32 + ks);
  bf16x8 tb1 = *(const bf16x8*)(wsb + rr*32 + 16 + ks);
  const u16* ub = u_s + (size_t)pair*1024;
  f32x16 wr;
  #pragma unroll
  for (int r=0;r<16;r++){
    int i = (r&3)+8*(r>>2)+4*hi;
    wr[r] = b2f(ub[i*32 + rr]);
  }
  const u16* rb = rn_s + (size_t)pair*1024;
  bf16x8 rn0 = *(const bf16x8*)(rb + rr*32 + ks);
  bf16x8 rn1 = *(const bf16x8*)(rb + rr*32 + 16 + ks);
  wr = __builtin_amdgcn_mfma_f32_32x32x16_bf16(rn0, tb0, wr, 0,0,0);
  wr = __builtin_amdgcn_mfma_f32_32x32x16_bf16(rn1, tb1, wr, 0,0,0);
  bf16x8 wb0, wb1;
  make_bfrags(wr, hi, wb0, wb1);
  __syncthreads();
  f32x16 o = zero16();
  o = __builtin_amdgcn_mfma_f32_32x32x16_bf16(q0, tb0, o, 0,0,0);
  o = __builtin_amdgcn_mfma_f32_32x32x16_bf16(q1, tb1, o, 0,0,0);
  bf16x8 pa0 = *(const bf16x8*)(Pl + rr*40 + ks);
  bf16x8 pa1 = *(const bf16x8*)(Pl + rr*40 + 16 + ks);
  o = __builtin_amdgcn_mfma_f32_32x32x16_bf16(pa0, wb0, o, 0,0,0);
  o = __builtin_amdgcn_mfma_f32_32x32x16_bf16(pa1, wb1, o, 0,0,0);
  int bb = head/NHc, nh = head - bb*NHc;
  #pragma unroll
  for (int reg=0;reg<16;reg++){
    int i = (reg&3)+8*(reg>>2)+4*hi;
    o_bf[((size_t)(bb*Lc + l0 + i))*Cc + nh*32 + rr] = f2b(o[reg]);
  }
}

// ---------------- launch ----------------
extern "C" void kernel_launch(void* const* d_in, const int* in_sizes, int n_in,
                              void* d_out, int out_size, void* d_ws, size_t ws_size,
                              hipStream_t stream){
  const float* x     = (const float*)d_in[0];
  const float* cpe_w = (const float*)d_in[1];
  const float* cpe_b = (const float*)d_in[2];
  const float* n1_g  = (const float*)d_in[3];
  const float* n1_b  = (const float*)d_in[4];
  const float* qkv_w = (const float*)d_in[5];
  const float* qkv_b = (const float*)d_in[6];
  const float* W0    = (const float*)d_in[7];
  const float* proj_w= (const float*)d_in[8];
  const float* proj_b= (const float*)d_in[9];
  const float* n2_g  = (const float*)d_in[10];
  const float* n2_b  = (const float*)d_in[11];
  const float* fc1_w = (const float*)d_in[12];
  const float* fc1_b = (const float*)d_in[13];
  const float* dwc_w = (const float*)d_in[14];
  const float* dwc_b = (const float*)d_in[15];
  const float* fc2_w = (const float*)d_in[16];
  const float* fc2_b = (const float*)d_in[17];

  char* ws = (char*)d_ws;
  size_t off = 0;
  auto alloc = [&](size_t bytes)->char*{
    char* p = ws + off;
    off += (bytes + 255) & ~(size_t)255;
    return p;
  };
  u16* wbqkv = (u16*)alloc((size_t)576*192*2);
  u16* wbproj= (u16*)alloc((size_t)192*192*2);
  u16* wbfc1 = (u16*)alloc((size_t)768*192*2);
  u16* wbfc2 = (u16*)alloc((size_t)192*768*2);
  float* dwt9 = (float*)alloc((size_t)9*HIDc*4);
  float* cwt9 = (float*)alloc((size_t)9*Cc*4);
  float* ctab = (float*)alloc((size_t)Lc*96*4);
  float* stab = (float*)alloc((size_t)Lc*96*4);
  u16* regA = (u16*)alloc((size_t)ROWS*Cc*2);       // x1 -> x2b (elementwise in-place at proj)
  u16* regB = (u16*)alloc((size_t)ROWS*Cc*2);       // xn -> obf -> xn2 (row-local at proj)
  u16* regC = (u16*)alloc((size_t)NHEAD*Lc*DHc*2);  // qs
  u16* regD = (u16*)alloc((size_t)NHEAD*Lc*DHc*2);  // vs -> wsn -> h1[0:half]
  u16* regE = (u16*)alloc((size_t)NHEAD*Lc*DHc*2);  // ksb -> h1[half:]
  u16* rn_s = (u16*)alloc((size_t)NPAIR*1024*2);    // -R -> h2[0:half]
  u16* af_s = (u16*)alloc((size_t)NPAIR*1024*2);    // A' frags -> h2[half:]
  // d_out (38.5 MB): [us | bc] during TTT -> final fp32 output
  u16* us = (u16*)d_out;
  u16* bc = us + (size_t)NPAIR*1024;

  u16* x1 = regA;
  u16* x2b = regA;  // proj epilogue: elementwise read-resid-then-write, same thread
  u16* xn = regB;
  u16* obf = regB;
  u16* xn2 = regB;
  u16* qs = regC;
  u16* vs = regD;
  u16* wsn = regD;  // written by tttb after ttta fully consumed vs
  u16* ksb = regE;
  u16* h1 = regD;   // regD+regE contiguous = GR2*768*2 bytes per group
  u16* h2 = rn_s;   // rn_s+af_s contiguous = GR2*768*2 bytes per group

  prep_kernel<<<(451008+255)/256,256,0,stream>>>(qkv_w, proj_w, fc1_w, fc2_w, dwc_w, cpe_w,
                                                 wbqkv, wbproj, wbfc1, wbfc2, dwt9, cwt9);
  rope_tab_kernel<<<(Lc*96)/256,256,0,stream>>>(ctab, stab);

  cpe_ln_kernel<<<ROWS/8,192,0,stream>>>(x, cwt9, cpe_b, n1_g, n1_b, x1, xn);
  gemm_kernel<0,3,192><<<ROWS/64,256,0,stream>>>(xn, wbqkv, qkv_b,
      nullptr, nullptr, vs, nullptr, ctab, stab, qs, ksb, nullptr, nullptr, nullptr);
  ttta_kernel<<<NPAIR,64,0,stream>>>(ksb, vs, us, rn_s, af_s, bc);
  tttb_kernel<<<NHEAD,64,0,stream>>>(af_s, bc, W0, wsn);
  tttc_kernel<<<NPAIR,64,0,stream>>>(qs, ksb, wsn, us, rn_s, obf);
  gemm_kernel<1,1,192><<<ROWS/64,256,0,stream>>>(obf, wbproj, proj_b,
      nullptr, x2b, nullptr, x1, nullptr, nullptr, nullptr, nullptr, n2_g, n2_b, xn2);
  for (int g4=0; g4<2; g4++){
    const u16* a_in = xn2 + (size_t)g4*GR2*Cc;
    float* xo = (float*)d_out + (size_t)g4*GR2*Cc;
    const u16* res = x2b + (size_t)g4*GR2*Cc;
    gemm_kernel<2,4,192><<<GR2/64,256,0,stream>>>(a_in, wbfc1, fc1_b,
        nullptr, h1, nullptr, nullptr, nullptr, nullptr, nullptr, nullptr, nullptr, nullptr, nullptr);
    dwc_kernel<<<(GR2*96)/256,256,0,stream>>>(h1, dwt9, dwc_b, h2, g4*GR2);
    gemm_kernel<3,1,768><<<GR2/64,256,0,stream>>>(h2, wbfc2, fc2_b,
        xo, nullptr, nullptr, res, nullptr, nullptr, nullptr, nullptr, nullptr, nullptr, nullptr);
  }
}

// Round 17
// 503.004 us; speedup vs baseline: 1.0208x; 1.0208x over previous
//
#include <hip/hip_runtime.h>
#include <hip/hip_bf16.h>

#define Bc 16
#define Hc 56
#define Wcc 56
#define Cc 192
#define NHc 6
#define Lc 3136
#define DHc 32
#define HIDc 768
#define NHEAD 96          // B*NH
#define Sc 32             // chunk length
#define NCHUNK 98         // chunks per head (98*32 = 3136)
#define NPAIR (NHEAD*NCHUNK)
#define ROWS (Bc*Lc)      // 50176
#define GR2 (ROWS/2)      // 25088 rows per MLP group (8 images)
#define ETAc (1.0f/32.0f)

typedef unsigned short u16;
typedef unsigned int u32;
typedef __attribute__((ext_vector_type(8))) short bf16x8;
typedef __attribute__((ext_vector_type(4))) float f32x4;
typedef __attribute__((ext_vector_type(16))) float f32x16;

__device__ __forceinline__ float b2f(u16 v){ u32 u = ((u32)v)<<16; float f; __builtin_memcpy(&f,&u,4); return f; }
__device__ __forceinline__ u16 f2b(float f){ u32 u; __builtin_memcpy(&u,&f,4); u32 r = u + 0x7FFFu + ((u>>16)&1u); return (u16)(r>>16); }
__device__ __forceinline__ f32x16 zero16(){ f32x16 z = {0,0,0,0,0,0,0,0,0,0,0,0,0,0,0,0}; return z; }

__device__ __forceinline__ void make_bfrags(const f32x16& t, int hi, bf16x8& b1, bf16x8& b2){
  u32 P[8], S[8];
  #pragma unroll
  for (int q=0;q<4;q++){
    #pragma unroll
    for (int j=0;j<2;j++){
      u32 r; float lo = t[4*q+2*j], hv = t[4*q+2*j+1];
      asm("v_cvt_pk_bf16_f32 %0, %1, %2" : "=v"(r) : "v"(lo), "v"(hv));
      P[2*q+j] = r;
    }
  }
  #pragma unroll
  for (int i=0;i<8;i++) S[i] = (u32)__shfl_xor((int)P[i], 32);
  union { u32 u[4]; bf16x8 v; } f1, f2;
  if (hi==0){ f1.u[0]=P[0]; f1.u[1]=P[1]; f1.u[2]=S[0]; f1.u[3]=S[1];
              f2.u[0]=P[4]; f2.u[1]=P[5]; f2.u[2]=S[4]; f2.u[3]=S[5]; }
  else      { f1.u[0]=S[2]; f1.u[1]=S[3]; f1.u[2]=P[2]; f1.u[3]=P[3];
              f2.u[0]=S[6]; f2.u[1]=S[7]; f2.u[2]=P[6]; f2.u[3]=P[7]; }
  b1 = f1.v; b2 = f2.v;
}

// ---------------- fused weight prep: 4 casts + 2 depthwise transposes ----------------
__global__ __launch_bounds__(256) void prep_kernel(
    const float* __restrict__ qkvw, const float* __restrict__ projw,
    const float* __restrict__ fc1w, const float* __restrict__ fc2w,
    const float* __restrict__ dwcw, const float* __restrict__ cpew,
    u16* __restrict__ wbqkv, u16* __restrict__ wbproj, u16* __restrict__ wbfc1,
    u16* __restrict__ wbfc2, float* __restrict__ dwt9, float* __restrict__ cwt9){
  int i = blockIdx.x*256 + threadIdx.x;
  if (i < 110592) wbqkv[i] = f2b(qkvw[i]);
  else if (i < 147456){ int j=i-110592; wbproj[j] = f2b(projw[j]); }
  else if (i < 294912){ int j=i-147456; wbfc1[j] = f2b(fc1w[j]); }
  else if (i < 442368){ int j=i-294912; wbfc2[j] = f2b(fc2w[j]); }
  else if (i < 449280){ int j=i-442368; int ch=j/9, t=j-ch*9; dwt9[t*HIDc+ch] = dwcw[j]; }
  else if (i < 451008){ int j=i-449280; int ch=j/9, t=j-ch*9; cwt9[t*Cc+ch] = cpew[j]; }
}

// ---------------- rope tables ----------------
__global__ __launch_bounds__(256) void rope_tab_kernel(float* __restrict__ ct, float* __restrict__ st){
  int i = blockIdx.x*256 + threadIdx.x;   // < Lc*96
  int l = i/96, p = i - l*96;
  int h = l/Wcc, w = l - h*Wcc;
  int kk = (p<48)? p : p-48;
  float th = powf(10000.f, -(float)kk/48.f);
  float ang = (float)((p<48)? h : w) * th;
  ct[i] = cosf(ang);
  st[i] = sinf(ang);
}

// ---------------- CPE depthwise conv + LN1 fused: block = 8 rows x 24 thr, 8 ch/thread ----------------
__global__ __launch_bounds__(192) void cpe_ln_kernel(const float* __restrict__ x, const float* __restrict__ cwt9,
                                                     const float* __restrict__ bs, const float* __restrict__ g,
                                                     const float* __restrict__ b,
                                                     u16* __restrict__ x1, u16* __restrict__ xn){
  __shared__ float ps[192], pq[192], smu[8], srs[8];
  int tid = threadIdx.x;
  int rl = tid/24, sub = tid - rl*24, ch0 = sub*8;
  int row = blockIdx.x*8 + rl;
  int l = row % Lc; int h = l/Wcc, w = l - h*Wcc;
  const float* xp = x + (size_t)row*Cc + ch0;
  float acc[8];
  { f32x4 b0 = *(const f32x4*)(bs+ch0), b1v = *(const f32x4*)(bs+ch0+4);
    acc[0]=b0[0];acc[1]=b0[1];acc[2]=b0[2];acc[3]=b0[3];
    acc[4]=b1v[0];acc[5]=b1v[1];acc[6]=b1v[2];acc[7]=b1v[3]; }
  #pragma unroll
  for (int kh=0;kh<3;kh++){
    int hh = h+kh-1; if (hh<0 || hh>=Hc) continue;
    #pragma unroll
    for (int kw=0;kw<3;kw++){
      int ww = w+kw-1; if (ww<0 || ww>=Wcc) continue;
      const float* ip = xp + ((kh-1)*Wcc + (kw-1))*Cc;
      f32x4 i0 = *(const f32x4*)ip, i1 = *(const f32x4*)(ip+4);
      const float* wp = cwt9 + (kh*3+kw)*Cc + ch0;
      f32x4 w0 = *(const f32x4*)wp, w1 = *(const f32x4*)(wp+4);
      acc[0] += i0[0]*w0[0]; acc[1] += i0[1]*w0[1]; acc[2] += i0[2]*w0[2]; acc[3] += i0[3]*w0[3];
      acc[4] += i1[0]*w1[0]; acc[5] += i1[1]*w1[1]; acc[6] += i1[2]*w1[2]; acc[7] += i1[3]*w1[3];
    }
  }
  float val[8];
  { f32x4 c0 = *(const f32x4*)xp, c1 = *(const f32x4*)(xp+4);
    val[0]=c0[0]+acc[0]; val[1]=c0[1]+acc[1]; val[2]=c0[2]+acc[2]; val[3]=c0[3]+acc[3];
    val[4]=c1[0]+acc[4]; val[5]=c1[1]+acc[5]; val[6]=c1[2]+acc[6]; val[7]=c1[3]+acc[7]; }
  float s8=0.f, q8=0.f;
  #pragma unroll
  for (int j=0;j<8;j++){ s8 += val[j]; q8 += val[j]*val[j]; }
  ps[tid]=s8; pq[tid]=q8;
  __syncthreads();
  if (tid < 8){
    float s=0.f, q=0.f;
    #pragma unroll
    for (int k=0;k<24;k++){ s += ps[tid*24+k]; q += pq[tid*24+k]; }
    float mu = s*(1.f/Cc);
    float var = q*(1.f/Cc) - mu*mu;
    smu[tid] = mu; srs[tid] = rsqrtf(var + 1e-5f);
  }
  __syncthreads();
  float mu = smu[rl], rstd = srs[rl];
  union { bf16x8 v; u16 s[8]; } o1, o2;
  f32x4 g0 = *(const f32x4*)(g+ch0), g1 = *(const f32x4*)(g+ch0+4);
  f32x4 bb0 = *(const f32x4*)(b+ch0), bb1 = *(const f32x4*)(b+ch0+4);
  float gg[8] = {g0[0],g0[1],g0[2],g0[3],g1[0],g1[1],g1[2],g1[3]};
  float bbv[8] = {bb0[0],bb0[1],bb0[2],bb0[3],bb1[0],bb1[1],bb1[2],bb1[3]};
  #pragma unroll
  for (int j=0;j<8;j++){
    o1.s[j] = f2b(val[j]);
    o2.s[j] = f2b((val[j]-mu)*rstd*gg[j] + bbv[j]);
  }
  *(bf16x8*)(x1 + (size_t)row*Cc + ch0) = o1.v;
  *(bf16x8*)(xn + (size_t)row*Cc + ch0) = o2.v;
}

// ---------------- LDS-staged GEMM, BLKM=64, coalesced LDS epilogue (grid-y column tiles) ----------------
// MODE 0: qkv + fused rope  (y=0: q->rope*scale->q_s; y=1: k->rope->k_s; y=2: v->vdst)
// MODE 1: proj: bf16 out = v + b2f(residb) AND fused LN2 -> xnout
// MODE 2: fc1:  bf16 out = gelu(v), width HIDc
// MODE 3: fc2:  fp32 out = v + b2f(residb)
template<int MODE, int KT>
__global__ __launch_bounds__(256) void gemm_kernel(
    const u16* __restrict__ A, const u16* __restrict__ Wt,
    const float* __restrict__ bias,
    float* __restrict__ outf, u16* __restrict__ outb, u16* __restrict__ vdst,
    const u16* __restrict__ residb,
    const float* __restrict__ ct, const float* __restrict__ st,
    u16* __restrict__ q_s, u16* __restrict__ k_s,
    const float* __restrict__ lng, const float* __restrict__ lnb, u16* __restrict__ xnout)
{
  constexpr int NCH = KT/192;
  __shared__ __align__(16) char smem[64*200*2];   // As[64][200] u16 | Os32[64][100] f32 | Osu[64][200] u16
  u16* As = (u16*)smem;
  float* Os32 = (float*)smem;
  u16* Osu = (u16*)smem;
  int tid = threadIdx.x;
  int wid = tid>>6, lane = tid&63;
  int wr = wid>>1, wc = wid&1;
  int m0 = blockIdx.x*64;
  int nblk = blockIdx.y*192;
  int n0 = nblk + wc*96;
  int ar = lane&15, kg = lane>>4;
  f32x4 acc[2][6];
  #pragma unroll
  for (int f=0;f<2;f++)
    #pragma unroll
    for (int c=0;c<6;c++){ f32x4 z = {0.f,0.f,0.f,0.f}; acc[f][c] = z; }
  bf16x8 bcur[6], bnxt[6];
  #pragma unroll
  for (int c=0;c<6;c++) bcur[c] = *(const bf16x8*)(Wt + (size_t)(n0 + c*16 + ar)*KT + kg*8);
  #pragma unroll
  for (int ch=0; ch<NCH; ch++){
    if (ch>0) __syncthreads();
    #pragma unroll
    for (int j=0;j<6;j++){
      int g = j*256 + tid;
      int grow = g/24, gcol = (g - grow*24)*8;
      bf16x8 v = *(const bf16x8*)(A + (size_t)(m0+grow)*KT + ch*192 + gcol);
      *(bf16x8*)(As + grow*200 + gcol) = v;
    }
    __syncthreads();
    #pragma unroll
    for (int kc=0;kc<6;kc++){
      int s = ch*6 + kc;
      if (s+1 < NCH*6){
        int koff = ((s+1)/6)*192 + ((s+1)%6)*32 + kg*8;
        #pragma unroll
        for (int c=0;c<6;c++) bnxt[c] = *(const bf16x8*)(Wt + (size_t)(n0 + c*16 + ar)*KT + koff);
      }
      bf16x8 af[2];
      #pragma unroll
      for (int f=0;f<2;f++)
        af[f] = *(const bf16x8*)(As + (wr*32 + f*16 + ar)*200 + kc*32 + kg*8);
      #pragma unroll
      for (int f=0;f<2;f++)
        #pragma unroll
        for (int c=0;c<6;c++)
          acc[f][c] = __builtin_amdgcn_mfma_f32_16x16x32_bf16(af[f], bcur[c], acc[f][c], 0,0,0);
      #pragma unroll
      for (int c=0;c<6;c++) bcur[c] = bnxt[c];
    }
  }
  __syncthreads();
  if (MODE != 3){
    #pragma unroll
    for (int f=0;f<2;f++){
      #pragma unroll
      for (int c=0;c<6;c++){
        float bv = bias[n0 + c*16 + ar];
        #pragma unroll
        for (int j=0;j<4;j++){
          float v = acc[f][c][j] + bv;
          if (MODE==2) v = 0.5f*v*(1.f + erff(v*0.70710678118654752f));
          Osu[(wr*32 + f*16 + kg*4 + j)*200 + wc*96 + c*16 + ar] = f2b(v);
        }
      }
    }
    __syncthreads();
    #pragma unroll
    for (int j=0;j<6;j++){
      int g = j*256 + tid;
      int grow = g/24, gcol = (g - grow*24)*8;
      bf16x8 v = *(const bf16x8*)(Osu + grow*200 + gcol);
      int row = m0 + grow;
      if (MODE==2){
        *(bf16x8*)(outb + (size_t)row*HIDc + nblk + gcol) = v;
      } else if (MODE==1){
        const u16* rp = residb + (size_t)row*Cc + gcol;
        bf16x8 rv = *(const bf16x8*)rp;
        union { bf16x8 v; u16 s[8]; } o;
        #pragma unroll
        for (int t=0;t<8;t++) o.s[t] = f2b(b2f((u16)v[t]) + b2f((u16)rv[t]));
        *(bf16x8*)(outb + (size_t)row*Cc + gcol) = o.v;
        *(bf16x8*)(Osu + grow*200 + gcol) = o.v;   // stash x2 (bf16) for fused LN2
      } else {   // MODE 0: qkv with fused rope
        int bb = row/Lc; int l = row - bb*Lc;
        int nh = gcol>>5, d = gcol&31;
        if (nblk < 384){
          bool isq = (nblk == 0);
          int p0 = gcol>>1;
          f32x4 cv = *(const f32x4*)(ct + l*96 + p0);
          f32x4 sv = *(const f32x4*)(st + l*96 + p0);
          float sc = isq ? 0.1767766952966369f : 1.0f;
          union { bf16x8 v; u16 s[8]; } o;
          #pragma unroll
          for (int t=0;t<4;t++){
            float re = b2f((u16)v[2*t]), im = b2f((u16)v[2*t+1]);
            o.s[2*t]   = f2b((cv[t]*re - sv[t]*im)*sc);
            o.s[2*t+1] = f2b((sv[t]*re + cv[t]*im)*sc);
          }
          u16* dst = (isq ? q_s : k_s) + (((size_t)(bb*NHc+nh))*Lc + l)*DHc + d;
          *(bf16x8*)dst = o.v;
        } else {
          *(bf16x8*)(vdst + (((size_t)(bb*NHc+nh))*Lc + l)*DHc + d) = v;
        }
      }
    }
    // ---- fused LN2 (MODE 1): per-row stats over Osu (x2 bf16), write xnout ----
    if (MODE==1){
      __syncthreads();
      int rowl = tid>>2, q = tid&3;        // 4 threads per row, 48 cols each
      const u16* orow = Osu + rowl*200 + q*48;
      float s=0.f, qq=0.f;
      #pragma unroll
      for (int c=0;c<48;c++){ float v = b2f(orow[c]); s += v; qq += v*v; }
      s += __shfl_xor(s,1); qq += __shfl_xor(qq,1);
      s += __shfl_xor(s,2); qq += __shfl_xor(qq,2);
      float mu = s*(1.f/192.f);
      float rstd = rsqrtf(qq*(1.f/192.f) - mu*mu + 1e-5f);
      int row = m0 + rowl;
      #pragma unroll
      for (int c8=0;c8<6;c8++){
        union { bf16x8 v; u16 s[8]; } ox;
        #pragma unroll
        for (int t=0;t<8;t++){
          int col = q*48 + c8*8 + t;
          ox.s[t] = f2b((b2f(orow[c8*8+t])-mu)*rstd*lng[col] + lnb[col]);
        }
        *(bf16x8*)(xnout + (size_t)row*Cc + q*48 + c8*8) = ox.v;
      }
    }
  } else {
    #pragma unroll
    for (int half=0; half<2; half++){
      if (wc==half){
        #pragma unroll
        for (int f=0;f<2;f++){
          #pragma unroll
          for (int c=0;c<6;c++){
            float bv = bias[n0 + c*16 + ar];
            #pragma unroll
            for (int j=0;j<4;j++)
              Os32[(wr*32 + f*16 + kg*4 + j)*100 + c*16 + ar] = acc[f][c][j] + bv;
          }
        }
      }
      __syncthreads();
      #pragma unroll
      for (int j=0;j<6;j++){
        int g = j*256 + tid;
        int grow = g/24, qcol = (g - grow*24)*4;
        f32x4 v = *(const f32x4*)(Os32 + grow*100 + qcol);
        int row = m0 + grow, colg = half*96 + qcol;
        const u16* rp = residb + (size_t)row*Cc + colg;
        v[0] += b2f(rp[0]); v[1] += b2f(rp[1]); v[2] += b2f(rp[2]); v[3] += b2f(rp[3]);
        *(f32x4*)(outf + (size_t)row*Cc + colg) = v;
      }
      if (half==0) __syncthreads();
    }
  }
}

// ---------------- phase A: per (head,chunk) solve -> U, -R, A'=-K^T R (frags), B=K^T U ----------------
__global__ __launch_bounds__(64) void ttta_kernel(const u16* __restrict__ k_s, const u16* __restrict__ v_s,
                                                  u16* __restrict__ u_s, u16* __restrict__ rn_s,
                                                  u16* __restrict__ af_s, u16* __restrict__ bc_s){
  __shared__ float Gl[1024];
  __shared__ u16 LK[32*40];
  __shared__ float LU[32*33];
  __shared__ float LR[32*33];
  int pair = blockIdx.x;
  int head = pair / NCHUNK;
  int l0 = (pair - head*NCHUNK) * Sc;
  int lane = threadIdx.x; int rr = lane&31; int hi = lane>>5; int ks = hi*8;
  const u16* kb = k_s + ((size_t)head*Lc + l0)*DHc;
  bf16x8 a0 = *(const bf16x8*)(kb + rr*32 + ks);
  bf16x8 a1 = *(const bf16x8*)(kb + rr*32 + 16 + ks);
  *(bf16x8*)(LK + rr*40 + ks) = a0;
  *(bf16x8*)(LK + rr*40 + 16 + ks) = a1;
  f32x16 g = zero16();
  g = __builtin_amdgcn_mfma_f32_32x32x16_bf16(a0, a0, g, 0,0,0);
  g = __builtin_amdgcn_mfma_f32_32x32x16_bf16(a1, a1, g, 0,0,0);
  #pragma unroll
  for (int reg=0;reg<16;reg++){
    int i = (reg&3) + 8*(reg>>2) + 4*hi;
    Gl[i*32 + rr] = ETAc * g[reg];
  }
  __syncthreads();
  float X[32];
  if (lane < 32){
    #pragma unroll
    for (int i=0;i<32;i++) X[i] = ETAc * b2f(v_s[((size_t)head*Lc + l0 + i)*DHc + lane]);
  } else {
    int m = lane-32;
    #pragma unroll
    for (int i=0;i<32;i++) X[i] = ETAc * b2f(kb[i*32 + m]);
  }
  #pragma unroll
  for (int i=1;i<32;i++){
    float a = X[i];
    #pragma unroll
    for (int j=0;j<i;j++) a -= Gl[i*32+j]*X[j];
    X[i] = a;
  }
  if (lane < 32){
    u16* dst = u_s + (size_t)pair*1024 + lane;
    #pragma unroll
    for (int i=0;i<32;i++) dst[i*32] = f2b(X[i]);
    #pragma unroll
    for (int i=0;i<32;i++) LU[lane*33 + i] = X[i];
  } else {
    u16* dst = rn_s + (size_t)pair*1024 + (lane&31);
    #pragma unroll
    for (int i=0;i<32;i++) dst[i*32] = f2b(-X[i]);
    #pragma unroll
    for (int i=0;i<32;i++) LR[(lane&31)*33 + i] = X[i];
  }
  __syncthreads();
  union { bf16x8 v; u16 s[8]; } kc1, kc2, uc1, uc2, rc1, rc2;
  #pragma unroll
  for (int s=0;s<8;s++){
    kc1.s[s] = LK[(ks+s)*40 + rr];
    kc2.s[s] = LK[(16+ks+s)*40 + rr];
    uc1.s[s] = f2b(LU[rr*33 + ks+s]);
    uc2.s[s] = f2b(LU[rr*33 + 16+ks+s]);
    rc1.s[s] = f2b(LR[rr*33 + ks+s]);
    rc2.s[s] = f2b(LR[rr*33 + 16+ks+s]);
  }
  f32x16 bacc = zero16();
  bacc = __builtin_amdgcn_mfma_f32_32x32x16_bf16(kc1.v, uc1.v, bacc, 0,0,0);
  bacc = __builtin_amdgcn_mfma_f32_32x32x16_bf16(kc2.v, uc2.v, bacc, 0,0,0);
  union { bf16x8 v; u16 s[8]; } bo1, bo2;
  #pragma unroll
  for (int r=0;r<8;r++){ bo1.s[r] = f2b(bacc[r]); bo2.s[r] = f2b(bacc[8+r]); }
  *(bf16x8*)(bc_s + (size_t)pair*1024 + lane*16) = bo1.v;
  *(bf16x8*)(bc_s + (size_t)pair*1024 + lane*16 + 8) = bo2.v;
  f32x16 aacc = zero16();
  aacc = __builtin_amdgcn_mfma_f32_32x32x16_bf16(rc1.v, kc1.v, aacc, 0,0,0);
  aacc = __builtin_amdgcn_mfma_f32_32x32x16_bf16(rc2.v, kc2.v, aacc, 0,0,0);
  f32x16 an;
  #pragma unroll
  for (int r=0;r<16;r++) an[r] = -aacc[r];
  bf16x8 f1, f2;
  make_bfrags(an, hi, f1, f2);
  *(bf16x8*)(af_s + (size_t)pair*1024 + lane*16) = f1;
  *(bf16x8*)(af_s + (size_t)pair*1024 + lane*16 + 8) = f2;
}

// ---------------- phase B: MFMA affine scan  T_{c+1} = T_c + A'_c T_c + B_c ----------------
__global__ __launch_bounds__(64) void tttb_kernel(const u16* __restrict__ af_s, const u16* __restrict__ bc_s,
                                                  const float* __restrict__ W0, u16* __restrict__ w_snap){
  int head = blockIdx.x; int nh = head % NHc;
  int lane = threadIdx.x; int rr = lane&31; int hi = lane>>5;
  f32x16 T;
  const float* w0r = W0 + nh*1024 + rr*32 + 4*hi;
  #pragma unroll
  for (int q=0;q<4;q++){
    f32x4 v = *(const f32x4*)(w0r + 8*q);
    T[4*q+0]=v[0]; T[4*q+1]=v[1]; T[4*q+2]=v[2]; T[4*q+3]=v[3];
  }
  size_t hb = (size_t)head*NCHUNK;
  const bf16x8* afp = (const bf16x8*)(af_s + hb*1024);
  const bf16x8* bcp = (const bf16x8*)(bc_s + hb*1024);
  bf16x8 A1 = afp[lane*2], A2 = afp[lane*2+1];
  bf16x8 Bv1 = bcp[lane*2], Bv2 = bcp[lane*2+1];
  bf16x8 b1, b2;
  make_bfrags(T, hi, b1, b2);
  for (int c=0;c<NCHUNK;c++){
    bf16x8 nA1=A1, nA2=A2, nB1=Bv1, nB2=Bv2;
    if (c+1 < NCHUNK){
      int base = (c+1)*128 + lane*2;
      nA1 = afp[base]; nA2 = afp[base+1];
      nB1 = bcp[base]; nB2 = bcp[base+1];
    }
    u16* wrow = w_snap + (hb + c)*1024 + rr*32;
    *(bf16x8*)(wrow + hi*8) = b1;
    *(bf16x8*)(wrow + 16 + hi*8) = b2;
    f32x16 acc;
    #pragma unroll
    for (int r=0;r<8;r++){ acc[r] = T[r] + b2f((u16)Bv1[r]); acc[8+r] = T[8+r] + b2f((u16)Bv2[r]); }
    acc = __builtin_amdgcn_mfma_f32_32x32x16_bf16(A1, b1, acc, 0,0,0);
    acc = __builtin_amdgcn_mfma_f32_32x32x16_bf16(A2, b2, acc, 0,0,0);
    T = acc;
    make_bfrags(T, hi, b1, b2);
    A1=nA1; A2=nA2; Bv1=nB1; Bv2=nB2;
  }
}

// ---------------- phase C: O = Q*T0 + tril(Q K^T)*(U - R*T0) ----------------
__global__ __launch_bounds__(64) void tttc_kernel(const u16* __restrict__ q_s, const u16* __restrict__ k_s,
                                                  const u16* __restrict__ w_snap, const u16* __restrict__ u_s,
                                                  const u16* __restrict__ rn_s, u16* __restrict__ o_bf){
  __shared__ __align__(16) u16 Pl[32*40];
  int pair = blockIdx.x;
  int head = pair / NCHUNK;
  int ch = pair - head*NCHUNK;
  int l0 = ch*Sc;
  int lane = threadIdx.x; int rr = lane&31; int hi = lane>>5; int ks = hi*8;
  const u16* qb = q_s + ((size_t)head*Lc + l0)*DHc;
  const u16* kb = k_s + ((size_t)head*Lc + l0)*DHc;
  bf16x8 q0 = *(const bf16x8*)(qb + rr*32 + ks);
  bf16x8 q1 = *(const bf16x8*)(qb + rr*32 + 16 + ks);
  bf16x8 k0 = *(const bf16x8*)(kb + rr*32 + ks);
  bf16x8 k1 = *(const bf16x8*)(kb + rr*32 + 16 + ks);
  f32x16 p = zero16();
  p = __builtin_amdgcn_mfma_f32_32x32x16_bf16(q0, k0, p, 0,0,0);
  p = __builtin_amdgcn_mfma_f32_32x32x16_bf16(q1, k1, p, 0,0,0);
  #pragma unroll
  for (int reg=0;reg<16;reg++){
    int i = (reg&3)+8*(reg>>2)+4*hi;
    Pl[i*40+rr] = (rr<=i) ? f2b(p[reg]) : (u16)0;
  }
  const u16* wsb = w_snap + (size_t)pair*1024;
  bf16x8 tb0 = *(const bf16x8*)(wsb + rr*32 + ks);
  bf16x8 tb1 = *(const bf16x8*)(wsb + rr*32 + 16 + ks);
  const u16* ub = u_s + (size_t)pair*1024;
  f32x16 wr;
  #pragma unroll
  for (int r=0;r<16;r++){
    int i = (r&3)+8*(r>>2)+4*hi;
    wr[r] = b2f(ub[i*32 + rr]);
  }
  const u16* rb = rn_s + (size_t)pair*1024;
  bf16x8 rn0 = *(const bf16x8*)(rb + rr*32 + ks);
  bf16x8 rn1 = *(const bf16x8*)(rb + rr*32 + 16 + ks);
  wr = __builtin_amdgcn_mfma_f32_32x32x16_bf16(rn0, tb0, wr, 0,0,0);
  wr = __builtin_amdgcn_mfma_f32_32x32x16_bf16(rn1, tb1, wr, 0,0,0);
  bf16x8 wb0, wb1;
  make_bfrags(wr, hi, wb0, wb1);
  __syncthreads();
  f32x16 o = zero16();
  o = __builtin_amdgcn_mfma_f32_32x32x16_bf16(q0, tb0, o, 0,0,0);
  o = __builtin_amdgcn_mfma_f32_32x32x16_bf16(q1, tb1, o, 0,0,0);
  bf16x8 pa0 = *(const bf16x8*)(Pl + rr*40 + ks);
  bf16x8 pa1 = *(const bf16x8*)(Pl + rr*40 + 16 + ks);
  o = __builtin_amdgcn_mfma_f32_32x32x16_bf16(pa0, wb0, o, 0,0,0);
  o = __builtin_amdgcn_mfma_f32_32x32x16_bf16(pa1, wb1, o, 0,0,0);
  int bb = head/NHc, nh = head - bb*NHc;
  #pragma unroll
  for (int reg=0;reg<16;reg++){
    int i = (reg&3)+8*(reg>>2)+4*hi;
    o_bf[((size_t)(bb*Lc + l0 + i))*Cc + nh*32 + rr] = f2b(o[reg]);
  }
}

// ---------------- MLP depthwise conv (HID=768) + gelu, 8 channels/thread ----------------
__global__ __launch_bounds__(256) void dwc_kernel(const u16* __restrict__ h1, const float* __restrict__ wt9,
                                                  const float* __restrict__ bs, u16* __restrict__ h2, int row0){
  int gid = blockIdx.x*256 + threadIdx.x;   // < GR2*96
  int cg = gid % 96; int lrow = gid / 96; int ch0 = cg*8;
  int row = row0 + lrow;
  int l = row % Lc; int h = l/Wcc, w = l - h*Wcc;
  const u16* hp = h1 + (size_t)lrow*HIDc + ch0;
  float acc[8];
  { f32x4 b0 = *(const f32x4*)(bs+ch0), b1v = *(const f32x4*)(bs+ch0+4);
    acc[0]=b0[0];acc[1]=b0[1];acc[2]=b0[2];acc[3]=b0[3];
    acc[4]=b1v[0];acc[5]=b1v[1];acc[6]=b1v[2];acc[7]=b1v[3]; }
  #pragma unroll
  for (int kh=0;kh<3;kh++){
    int hh = h+kh-1; if (hh<0 || hh>=Hc) continue;
    #pragma unroll
    for (int kw=0;kw<3;kw++){
      int ww = w+kw-1; if (ww<0 || ww>=Wcc) continue;
      bf16x8 iv = *(const bf16x8*)(hp + ((kh-1)*Wcc + (kw-1))*HIDc);
      const float* wp = wt9 + (kh*3+kw)*HIDc + ch0;
      f32x4 w0 = *(const f32x4*)wp, w1 = *(const f32x4*)(wp+4);
      acc[0] += b2f((u16)iv[0])*w0[0]; acc[1] += b2f((u16)iv[1])*w0[1];
      acc[2] += b2f((u16)iv[2])*w0[2]; acc[3] += b2f((u16)iv[3])*w0[3];
      acc[4] += b2f((u16)iv[4])*w1[0]; acc[5] += b2f((u16)iv[5])*w1[1];
      acc[6] += b2f((u16)iv[6])*w1[2]; acc[7] += b2f((u16)iv[7])*w1[3];
    }
  }
  bf16x8 cv = *(const bf16x8*)hp;
  union { bf16x8 v; u16 s[8]; } ov;
  #pragma unroll
  for (int j=0;j<8;j++){
    float v = b2f((u16)cv[j]) + acc[j];
    ov.s[j] = f2b(0.5f*v*(1.f + erff(v*0.70710678118654752f)));
  }
  *(bf16x8*)(h2 + (size_t)lrow*HIDc + ch0) = ov.v;
}

// ---------------- launch ----------------
extern "C" void kernel_launch(void* const* d_in, const int* in_sizes, int n_in,
                              void* d_out, int out_size, void* d_ws, size_t ws_size,
                              hipStream_t stream){
  const float* x     = (const float*)d_in[0];
  const float* cpe_w = (const float*)d_in[1];
  const float* cpe_b = (const float*)d_in[2];
  const float* n1_g  = (const float*)d_in[3];
  const float* n1_b  = (const float*)d_in[4];
  const float* qkv_w = (const float*)d_in[5];
  const float* qkv_b = (const float*)d_in[6];
  const float* W0    = (const float*)d_in[7];
  const float* proj_w= (const float*)d_in[8];
  const float* proj_b= (const float*)d_in[9];
  const float* n2_g  = (const float*)d_in[10];
  const float* n2_b  = (const float*)d_in[11];
  const float* fc1_w = (const float*)d_in[12];
  const float* fc1_b = (const float*)d_in[13];
  const float* dwc_w = (const float*)d_in[14];
  const float* dwc_b = (const float*)d_in[15];
  const float* fc2_w = (const float*)d_in[16];
  const float* fc2_b = (const float*)d_in[17];

  char* ws = (char*)d_ws;
  size_t off = 0;
  auto alloc = [&](size_t bytes)->char*{
    char* p = ws + off;
    off += (bytes + 255) & ~(size_t)255;
    return p;
  };
  u16* wbqkv = (u16*)alloc((size_t)576*192*2);
  u16* wbproj= (u16*)alloc((size_t)192*192*2);
  u16* wbfc1 = (u16*)alloc((size_t)768*192*2);
  u16* wbfc2 = (u16*)alloc((size_t)192*768*2);
  float* dwt9 = (float*)alloc((size_t)9*HIDc*4);
  float* cwt9 = (float*)alloc((size_t)9*Cc*4);
  float* ctab = (float*)alloc((size_t)Lc*96*4);
  float* stab = (float*)alloc((size_t)Lc*96*4);
  u16* regA = (u16*)alloc((size_t)ROWS*Cc*2);       // x1 -> x2b (elementwise in-place at proj)
  u16* regB = (u16*)alloc((size_t)ROWS*Cc*2);       // xn -> obf -> xn2 (row-local at proj)
  u16* regC = (u16*)alloc((size_t)NHEAD*Lc*DHc*2);  // qs
  u16* regD = (u16*)alloc((size_t)NHEAD*Lc*DHc*2);  // vs -> wsn -> h1[0:half]
  u16* regE = (u16*)alloc((size_t)NHEAD*Lc*DHc*2);  // ksb -> h1[half:]
  u16* rn_s = (u16*)alloc((size_t)NPAIR*1024*2);    // -R -> h2[0:half]
  u16* af_s = (u16*)alloc((size_t)NPAIR*1024*2);    // A' frags -> h2[half:]
  // d_out (38.5 MB): [us | bc] during TTT -> final fp32 output
  u16* us = (u16*)d_out;
  u16* bc = us + (size_t)NPAIR*1024;

  u16* x1 = regA;
  u16* x2b = regA;  // proj epilogue: elementwise read-resid-then-write, same address, same thread
  u16* xn = regB;
  u16* obf = regB;
  u16* xn2 = regB;
  u16* qs = regC;
  u16* vs = regD;
  u16* wsn = regD;  // written by tttb after ttta fully consumed vs
  u16* ksb = regE;
  u16* h1 = regD;   // regD+regE contiguous = GR2*768*2 bytes
  u16* h2 = rn_s;   // rn_s+af_s contiguous = GR2*768*2 bytes

  prep_kernel<<<(451008+255)/256,256,0,stream>>>(qkv_w, proj_w, fc1_w, fc2_w, dwc_w, cpe_w,
                                                 wbqkv, wbproj, wbfc1, wbfc2, dwt9, cwt9);
  rope_tab_kernel<<<(Lc*96)/256,256,0,stream>>>(ctab, stab);

  cpe_ln_kernel<<<ROWS/8,192,0,stream>>>(x, cwt9, cpe_b, n1_g, n1_b, x1, xn);
  { dim3 g(ROWS/64, 3); gemm_kernel<0,192><<<g,256,0,stream>>>(xn, wbqkv, qkv_b,
      nullptr, nullptr, vs, nullptr, ctab, stab, qs, ksb, nullptr, nullptr, nullptr); }
  ttta_kernel<<<NPAIR,64,0,stream>>>(ksb, vs, us, rn_s, af_s, bc);
  tttb_kernel<<<NHEAD,64,0,stream>>>(af_s, bc, W0, wsn);
  tttc_kernel<<<NPAIR,64,0,stream>>>(qs, ksb, wsn, us, rn_s, obf);
  { dim3 g(ROWS/64, 1); gemm_kernel<1,192><<<g,256,0,stream>>>(obf, wbproj, proj_b,
      nullptr, x2b, nullptr, x1, nullptr, nullptr, nullptr, nullptr, n2_g, n2_b, xn2); }
  for (int g4=0; g4<2; g4++){
    const u16* a_in = xn2 + (size_t)g4*GR2*Cc;
    float* xo = (float*)d_out + (size_t)g4*GR2*Cc;
    const u16* res = x2b + (size_t)g4*GR2*Cc;
    { dim3 g(GR2/64, 4); gemm_kernel<2,192><<<g,256,0,stream>>>(a_in, wbfc1, fc1_b,
        nullptr, h1, nullptr, nullptr, nullptr, nullptr, nullptr, nullptr, nullptr, nullptr, nullptr); }
    dwc_kernel<<<(GR2*96)/256,256,0,stream>>>(h1, dwt9, dwc_b, h2, g4*GR2);
    { dim3 g(GR2/64, 1); gemm_kernel<3,768><<<g,256,0,stream>>>(h2, wbfc2, fc2_b,
        xo, nullptr, nullptr, res, nullptr, nullptr, nullptr, nullptr, nullptr, nullptr, nullptr); }
  }
}